// Round 1
// baseline (662.581 us; speedup 1.0000x reference)
//
#include <hip/hip_runtime.h>

#define BATCH 1024
#define NV 3889
#define V3 11667
#define NJ 35
#define NK 336
#define VPS 11680  // padded v_posed row stride (mult of 32 floats -> float4 aligned)

// ws layout (floats)
#define WS_SJ 0          // 30*105
#define WS_J0 3152       // 105
#define WS_F 3264        // 1024*336
#define WS_JW 347328     // 1024*105
#define WS_SW 454848     // 1024*105
#define WS_AW 562368     // 1024*420
#define WS_VP 992448     // 1024*VPS

// d_out offsets (floats)
#define OUT_JOINTS 11947008
#define OUT_RS 12054528

__device__ const int d_parents[35] = {0,0,1,2,3,4,5,6,7,8,9,10,6,12,13,14,6,16,17,18,16,20,21,22,16,24,25,26,27,28,29,30,16,32,32};

__device__ const signed char d_scale_idx[105] = {
  -1,-1,-1, -1,-1,-1, -1,-1,-1, -1,-1,-1, -1,-1,-1, -1,-1,-1, -1,-1,-1, // j0..6
   1, 1, 0,  1, 1, 0,  1, 1, 0,  1, 1, 0,                               // j7..10
  -1,-1,-1, -1,-1,-1, -1,-1,-1, -1,-1,-1, -1,-1,-1,                     // j11..15
   6,-1,-1,                                                             // j16
   1, 1, 0,  1, 1, 0,  1, 1, 0,  1, 1, 0,                               // j17..20
  -1,-1,-1, -1,-1,-1, -1,-1,-1, -1,-1,-1,                               // j21..24
   2, 3, 3,  2, 3, 3,  2, 3, 3,  2, 3, 3,  2, 3, 3,  2, 3, 3,  2, 3, 3, // j25..31
  -1,-1,-1,                                                             // j32
  -1, 4, 5, -1, 4, 5                                                    // j33..34
};

// ---- SJ[k][jc] = sum_v shapedirs[k, v*3+c]*Jreg[v,j];  J0[jc] = sum_v v_template*Jreg
__global__ __launch_bounds__(256) void k_precomp(const float* __restrict__ shapedirs,
    const float* __restrict__ v_template, const float* __restrict__ Jreg,
    float* __restrict__ SJ, float* __restrict__ J0) {
  int idx = blockIdx.x * 256 + threadIdx.x;
  int vs = blockIdx.y * 487;
  int ve = min(NV, vs + 487);
  if (idx < 3150) {
    int k = idx / 105, jc = idx % 105;
    int j = jc / 3, c = jc % 3;
    float acc = 0.f;
    for (int v = vs; v < ve; ++v) acc += shapedirs[k * V3 + v * 3 + c] * Jreg[v * 35 + j];
    atomicAdd(&SJ[idx], acc);
  } else if (idx < 3255) {
    int jc = idx - 3150;
    int j = jc / 3, c = jc % 3;
    float acc = 0.f;
    for (int v = vs; v < ve; ++v) acc += v_template[v * 3 + c] * Jreg[v * 35 + j];
    atomicAdd(&J0[jc], acc);
  }
}

// ---- Rodrigues: Rs to d_out, pose_feature into f[b][30..335]
__global__ __launch_bounds__(256) void k_rodrig(const float* __restrict__ theta,
    float* __restrict__ rs_out, float* __restrict__ f) {
  int idx = blockIdx.x * 256 + threadIdx.x;
  if (idx >= BATCH * NJ) return;
  int b = idx / NJ, j = idx - b * NJ;
  float x = theta[idx * 3 + 0], y = theta[idx * 3 + 1], z = theta[idx * 3 + 2];
  float ax = x + 1e-8f, ay = y + 1e-8f, az = z + 1e-8f;
  float angle = sqrtf(ax * ax + ay * ay + az * az);
  float inv = 1.f / angle;
  float rx = x * inv, ry = y * inv, rz = z * inv;
  float c = cosf(angle), s = sinf(angle), ic = 1.f - c;
  float R[9];
  R[0] = c + ic * rx * rx;      R[1] = ic * rx * ry - s * rz; R[2] = ic * rx * rz + s * ry;
  R[3] = ic * ry * rx + s * rz; R[4] = c + ic * ry * ry;      R[5] = ic * ry * rz - s * rx;
  R[6] = ic * rz * rx - s * ry; R[7] = ic * rz * ry + s * rx; R[8] = c + ic * rz * rz;
  float* ro = rs_out + (size_t)idx * 9;
  #pragma unroll
  for (int e = 0; e < 9; ++e) ro[e] = R[e];
  if (j > 0) {
    float* fp = f + b * NK + 30 + (j - 1) * 9;
    #pragma unroll
    for (int e = 0; e < 9; ++e) fp[e] = R[e] - ((e == 0 || e == 4 || e == 8) ? 1.f : 0.f);
  }
}

// ---- J = J0 + beta@SJ ; scales = exp(mask-gather of betas_limbs) ; f[b][0..29] = beta
__global__ __launch_bounds__(256) void k_jscale(const float* __restrict__ beta,
    const float* __restrict__ bl, const float* __restrict__ SJ, const float* __restrict__ J0,
    float* __restrict__ Jw, float* __restrict__ Sw, float* __restrict__ f) {
  int idx = blockIdx.x * 256 + threadIdx.x;
  if (idx >= BATCH * 105) return;
  int b = idx / 105, jc = idx - b * 105;
  const float* be = beta + b * 30;
  float acc = J0[jc];
  #pragma unroll
  for (int k = 0; k < 30; ++k) acc += be[k] * SJ[k * 105 + jc];
  Jw[idx] = acc;
  int si = d_scale_idx[jc];
  Sw[idx] = (si >= 0) ? expf(bl[b * 7 + si]) : 1.f;
  if (jc < 30) f[b * NK + jc] = be[jc];
}

// ---- kinematic chain: one thread per batch; A[b][35][12] = [R_glob(9), t_adj(3)]
__global__ void k_chain(const float* __restrict__ rs, const float* __restrict__ Jw,
                        const float* __restrict__ Sw, float* __restrict__ Aw) {
  int b = blockIdx.x * blockDim.x + threadIdx.x;
  if (b >= BATCH) return;
  const float* Rsb = rs + (size_t)b * 315;
  const float* Jb = Jw + b * 105;
  const float* Sb = Sw + b * 105;
  float* A = Aw + b * 420;
  #pragma unroll
  for (int e = 0; e < 9; ++e) A[e] = Rsb[e];
  A[9] = Jb[0]; A[10] = Jb[1]; A[11] = Jb[2];
  for (int i = 1; i < 35; ++i) {
    int p = d_parents[i];
    const float* Ap = A + p * 12;
    float Rp[9], tp[3];
    #pragma unroll
    for (int e = 0; e < 9; ++e) Rp[e] = Ap[e];
    tp[0] = Ap[9]; tp[1] = Ap[10]; tp[2] = Ap[11];
    float sc[3] = {Sb[i * 3], Sb[i * 3 + 1], Sb[i * 3 + 2]};
    float ip[3] = {1.f / Sb[p * 3], 1.f / Sb[p * 3 + 1], 1.f / Sb[p * 3 + 2]};
    float Ri[9];
    #pragma unroll
    for (int r = 0; r < 3; ++r)
      #pragma unroll
      for (int cc = 0; cc < 3; ++cc)
        Ri[r * 3 + cc] = Rsb[i * 9 + r * 3 + cc] * sc[cc] * ip[r];
    float ti[3] = {Jb[i * 3] - Jb[p * 3], Jb[i * 3 + 1] - Jb[p * 3 + 1], Jb[i * 3 + 2] - Jb[p * 3 + 2]};
    float* Ai = A + i * 12;
    #pragma unroll
    for (int r = 0; r < 3; ++r) {
      #pragma unroll
      for (int cc = 0; cc < 3; ++cc)
        Ai[r * 3 + cc] = Rp[r * 3] * Ri[cc] + Rp[r * 3 + 1] * Ri[3 + cc] + Rp[r * 3 + 2] * Ri[6 + cc];
      Ai[9 + r] = Rp[r * 3] * ti[0] + Rp[r * 3 + 1] * ti[1] + Rp[r * 3 + 2] * ti[2] + tp[r];
    }
  }
  // adjust: t -= R_glob @ J
  for (int i = 0; i < 35; ++i) {
    float* Ai = A + i * 12;
    float jx = Jb[i * 3], jy = Jb[i * 3 + 1], jz = Jb[i * 3 + 2];
    float a0 = Ai[9] - (Ai[0] * jx + Ai[1] * jy + Ai[2] * jz);
    float a1 = Ai[10] - (Ai[3] * jx + Ai[4] * jy + Ai[5] * jz);
    float a2 = Ai[11] - (Ai[6] * jx + Ai[7] * jy + Ai[8] * jz);
    Ai[9] = a0; Ai[10] = a1; Ai[11] = a2;
  }
}

// ---- big GEMM: v_posed[b, col] = v_template[col] + sum_k f[b,k]*D[k,col]
// 128x128 tile, Kc=48, 8x8 per-thread register blocking
__global__ __launch_bounds__(256) void k_gemm(const float* __restrict__ f,
    const float* __restrict__ shapedirs, const float* __restrict__ posedirs,
    const float* __restrict__ v_template, float* __restrict__ v_posed) {
  __shared__ float fT[48][140];  // [k][row]
  __shared__ float Dl[48][136];  // [k][col]
  int tid = threadIdx.x;
  int n0 = blockIdx.x * 128;
  int b0 = blockIdx.y * 128;
  int tx = tid & 15, ty = tid >> 4;
  float acc[8][8];
  #pragma unroll
  for (int r = 0; r < 8; ++r)
    #pragma unroll
    for (int c = 0; c < 8; ++c) acc[r][c] = 0.f;
  for (int kt = 0; kt < 7; ++kt) {
    int k0 = kt * 48;
    for (int i = tid; i < 6144; i += 256) {
      int k = i % 48, row = i / 48;
      fT[k][row] = f[(b0 + row) * NK + k0 + k];
    }
    for (int i = tid; i < 6144; i += 256) {
      int col = i & 127, k = i >> 7;
      int gc = n0 + col, gk = k0 + k;
      float v = 0.f;
      if (gc < V3) v = (gk < 30) ? shapedirs[gk * V3 + gc] : posedirs[(size_t)(gk - 30) * V3 + gc];
      Dl[k][col] = v;
    }
    __syncthreads();
    #pragma unroll 4
    for (int k = 0; k < 48; ++k) {
      float4 a0 = *(const float4*)&fT[k][ty * 8];
      float4 a1 = *(const float4*)&fT[k][ty * 8 + 4];
      float4 q0 = *(const float4*)&Dl[k][tx * 8];
      float4 q1 = *(const float4*)&Dl[k][tx * 8 + 4];
      float av[8] = {a0.x, a0.y, a0.z, a0.w, a1.x, a1.y, a1.z, a1.w};
      float bv[8] = {q0.x, q0.y, q0.z, q0.w, q1.x, q1.y, q1.z, q1.w};
      #pragma unroll
      for (int r = 0; r < 8; ++r)
        #pragma unroll
        for (int c = 0; c < 8; ++c) acc[r][c] += av[r] * bv[c];
    }
    __syncthreads();
  }
  int col = n0 + tx * 8;
  float tv[8];
  #pragma unroll
  for (int c = 0; c < 8; ++c) tv[c] = (col + c < V3) ? v_template[col + c] : 0.f;
  #pragma unroll
  for (int r = 0; r < 8; ++r) {
    int row = b0 + ty * 8 + r;
    float* dst = v_posed + (size_t)row * VPS + col;
    if (col + 8 <= V3) {
      float4 o0 = make_float4(acc[r][0] + tv[0], acc[r][1] + tv[1], acc[r][2] + tv[2], acc[r][3] + tv[3]);
      float4 o1 = make_float4(acc[r][4] + tv[4], acc[r][5] + tv[5], acc[r][6] + tv[6], acc[r][7] + tv[7]);
      *(float4*)dst = o0;
      *(float4*)(dst + 4) = o1;
    } else {
      #pragma unroll
      for (int c = 0; c < 8; ++c)
        if (col + c < V3) dst[c] = acc[r][c] + tv[c];
    }
  }
}

// ---- skinning: verts = (sum_j w*A_R)@p + sum_j w*A_t + trans
// block: 4 batches (1 wave each) x 256 verts; 4 verts per lane
__global__ __launch_bounds__(256) void k_skin(const float* __restrict__ Aw,
    const float* __restrict__ weights, const float* __restrict__ v_posed,
    const float* __restrict__ trans, float* __restrict__ verts) {
  __shared__ float wl[256][37];
  __shared__ float Al[4][420];
  int tid = threadIdx.x;
  int v0 = blockIdx.x * 256;
  int b0 = blockIdx.y * 4;
  for (int i = tid; i < 256 * 35; i += 256) {
    int vl = i / 35, j = i - vl * 35;
    int v = v0 + vl;
    wl[vl][j] = (v < NV) ? weights[v * 35 + j] : 0.f;
  }
  for (int i = tid; i < 4 * 420; i += 256) {
    int b = i / 420, e = i - b * 420;
    Al[b][e] = Aw[(b0 + b) * 420 + e];
  }
  __syncthreads();
  int bb = tid >> 6, l = tid & 63;
  int gb = b0 + bb;
  float M[4][12];
  #pragma unroll
  for (int q = 0; q < 4; ++q)
    #pragma unroll
    for (int e = 0; e < 12; ++e) M[q][e] = 0.f;
  for (int j = 0; j < 35; ++j) {
    float4 A0 = *(const float4*)&Al[bb][j * 12];
    float4 A1 = *(const float4*)&Al[bb][j * 12 + 4];
    float4 A2 = *(const float4*)&Al[bb][j * 12 + 8];
    #pragma unroll
    for (int q = 0; q < 4; ++q) {
      float wj = wl[l + 64 * q][j];
      M[q][0] += wj * A0.x; M[q][1] += wj * A0.y; M[q][2] += wj * A0.z; M[q][3] += wj * A0.w;
      M[q][4] += wj * A1.x; M[q][5] += wj * A1.y; M[q][6] += wj * A1.z; M[q][7] += wj * A1.w;
      M[q][8] += wj * A2.x; M[q][9] += wj * A2.y; M[q][10] += wj * A2.z; M[q][11] += wj * A2.w;
    }
  }
  float t0 = trans[gb * 3], t1 = trans[gb * 3 + 1], t2 = trans[gb * 3 + 2];
  #pragma unroll
  for (int q = 0; q < 4; ++q) {
    int v = v0 + l + 64 * q;
    if (v < NV) {
      const float* p = &v_posed[(size_t)gb * VPS + v * 3];
      float p0 = p[0], p1 = p[1], p2 = p[2];
      float* o = verts + (size_t)gb * V3 + v * 3;
      o[0] = M[q][0] * p0 + M[q][1] * p1 + M[q][2] * p2 + M[q][9] + t0;
      o[1] = M[q][3] * p0 + M[q][4] * p1 + M[q][5] * p2 + M[q][10] + t1;
      o[2] = M[q][6] * p0 + M[q][7] * p1 + M[q][8] * p2 + M[q][11] + t2;
    }
  }
}

// ---- joints_red = verts . J_regressor  (atomic partial sums over v-slices)
__global__ __launch_bounds__(256) void k_joints(const float* __restrict__ verts,
    const float* __restrict__ Jreg, float* __restrict__ joints) {
  __shared__ float vt_lds[16][388];
  __shared__ float jr_lds[128][36];
  int tid = threadIdx.x;
  int b0 = blockIdx.x * 16;
  int vstart = blockIdx.y * 487;
  int vend = min(NV, vstart + 487);
  int bl = tid & 15, jg = tid >> 4;
  int j0 = jg, j1 = jg + 16, j2 = jg + 32;
  bool has2 = (j2 < 35);
  float acc[3][3];
  #pragma unroll
  for (int s = 0; s < 3; ++s)
    #pragma unroll
    for (int c = 0; c < 3; ++c) acc[s][c] = 0.f;
  for (int vt = vstart; vt < vend; vt += 128) {
    int nv = min(128, vend - vt);
    for (int i = tid; i < 16 * 384; i += 256) {
      int bb = i / 384, e = i - bb * 384;
      float val = 0.f;
      if (e < nv * 3) val = verts[(size_t)(b0 + bb) * V3 + vt * 3 + e];
      vt_lds[bb][e] = val;
    }
    for (int i = tid; i < 128 * 35; i += 256) {
      int vl = i / 35, j = i - vl * 35;
      int v = vt + vl;
      jr_lds[vl][j] = (v < vend) ? Jreg[v * 35 + j] : 0.f;
    }
    __syncthreads();
    for (int v = 0; v < nv; ++v) {
      float p0 = vt_lds[bl][v * 3 + 0];
      float p1 = vt_lds[bl][v * 3 + 1];
      float p2 = vt_lds[bl][v * 3 + 2];
      float jr0 = jr_lds[v][j0];
      acc[0][0] += jr0 * p0; acc[0][1] += jr0 * p1; acc[0][2] += jr0 * p2;
      float jr1 = jr_lds[v][j1];
      acc[1][0] += jr1 * p0; acc[1][1] += jr1 * p1; acc[1][2] += jr1 * p2;
      if (has2) {
        float jr2 = jr_lds[v][j2];
        acc[2][0] += jr2 * p0; acc[2][1] += jr2 * p1; acc[2][2] += jr2 * p2;
      }
    }
    __syncthreads();
  }
  int gb = b0 + bl;
  atomicAdd(&joints[gb * 105 + j0 * 3 + 0], acc[0][0]);
  atomicAdd(&joints[gb * 105 + j0 * 3 + 1], acc[0][1]);
  atomicAdd(&joints[gb * 105 + j0 * 3 + 2], acc[0][2]);
  atomicAdd(&joints[gb * 105 + j1 * 3 + 0], acc[1][0]);
  atomicAdd(&joints[gb * 105 + j1 * 3 + 1], acc[1][1]);
  atomicAdd(&joints[gb * 105 + j1 * 3 + 2], acc[1][2]);
  if (has2) {
    atomicAdd(&joints[gb * 105 + j2 * 3 + 0], acc[2][0]);
    atomicAdd(&joints[gb * 105 + j2 * 3 + 1], acc[2][1]);
    atomicAdd(&joints[gb * 105 + j2 * 3 + 2], acc[2][2]);
  }
}

extern "C" void kernel_launch(void* const* d_in, const int* in_sizes, int n_in,
                              void* d_out, int out_size, void* d_ws, size_t ws_size,
                              hipStream_t stream) {
  const float* beta = (const float*)d_in[0];
  const float* betas_limbs = (const float*)d_in[1];
  const float* theta = (const float*)d_in[2];
  const float* trans = (const float*)d_in[3];
  const float* v_template = (const float*)d_in[4];
  const float* shapedirs = (const float*)d_in[5];
  const float* Jreg = (const float*)d_in[6];
  const float* posedirs = (const float*)d_in[7];
  const float* weights = (const float*)d_in[8];

  float* out = (float*)d_out;
  float* verts = out;
  float* joints = out + OUT_JOINTS;
  float* rsout = out + OUT_RS;

  float* ws = (float*)d_ws;
  float* SJ = ws + WS_SJ;
  float* J0 = ws + WS_J0;
  float* f = ws + WS_F;
  float* Jw = ws + WS_JW;
  float* Sw = ws + WS_SW;
  float* Aw = ws + WS_AW;
  float* vposed = ws + WS_VP;

  hipMemsetAsync(ws, 0, 3264 * sizeof(float), stream);             // SJ + J0
  hipMemsetAsync(joints, 0, BATCH * 105 * sizeof(float), stream);  // joints accumulators

  k_precomp<<<dim3(13, 8), 256, 0, stream>>>(shapedirs, v_template, Jreg, SJ, J0);
  k_rodrig<<<140, 256, 0, stream>>>(theta, rsout, f);
  k_jscale<<<420, 256, 0, stream>>>(beta, betas_limbs, SJ, J0, Jw, Sw, f);
  k_chain<<<16, 64, 0, stream>>>(rsout, Jw, Sw, Aw);
  k_gemm<<<dim3(92, 8), 256, 0, stream>>>(f, shapedirs, posedirs, v_template, vposed);
  k_skin<<<dim3(16, 256), 256, 0, stream>>>(Aw, weights, vposed, trans, verts);
  k_joints<<<dim3(64, 8), 256, 0, stream>>>(verts, Jreg, joints);
}

// Round 4
// 491.269 us; speedup vs baseline: 1.3487x; 1.3487x over previous
//
#include <hip/hip_runtime.h>

#define BATCH 1024
#define NV 3889
#define V3 11667
#define NJ 35
#define NK 336
#define VPS 11680  // padded v_posed row stride (mult of 32 floats -> float4 aligned)

// ws layout (floats)
#define WS_SJ 0          // 30*105
#define WS_J0 3152       // 105
#define WS_F 3264        // 1024*336
#define WS_JW 347328     // 1024*105
#define WS_SW 454848     // 1024*105
#define WS_AW 562368     // 1024*420
#define WS_VP 992448     // 1024*VPS

// d_out offsets (floats)
#define OUT_JOINTS 11947008
#define OUT_RS 12054528

__device__ const signed char d_scale_idx[105] = {
  -1,-1,-1, -1,-1,-1, -1,-1,-1, -1,-1,-1, -1,-1,-1, -1,-1,-1, -1,-1,-1, // j0..6
   1, 1, 0,  1, 1, 0,  1, 1, 0,  1, 1, 0,                               // j7..10
  -1,-1,-1, -1,-1,-1, -1,-1,-1, -1,-1,-1, -1,-1,-1,                     // j11..15
   6,-1,-1,                                                             // j16
   1, 1, 0,  1, 1, 0,  1, 1, 0,  1, 1, 0,                               // j17..20
  -1,-1,-1, -1,-1,-1, -1,-1,-1, -1,-1,-1,                               // j21..24
   2, 3, 3,  2, 3, 3,  2, 3, 3,  2, 3, 3,  2, 3, 3,  2, 3, 3,  2, 3, 3, // j25..31
  -1,-1,-1,                                                             // j32
  -1, 4, 5, -1, 4, 5                                                    // j33..34
};

// ---- SJ[k][j*3+c] = sum_v shapedirs[k, v*3+c]*Jreg[v,j];  J0 likewise from v_template
// Split-K over v: 31 blocks x 128 verts (2 subtiles of 64), LDS-staged, atomic reduce.
__global__ __launch_bounds__(256) void k_precomp(const float* __restrict__ shapedirs,
    const float* __restrict__ v_template, const float* __restrict__ Jreg,
    float* __restrict__ SJ, float* __restrict__ J0) {
  __shared__ float As[64][96];  // [vi][m], m = k*3+c (0..89), 90..92 = v_template
  __shared__ float Jl[64][36];  // [vi][j]
  int tid = threadIdx.x;
  float acc[13];
  #pragma unroll
  for (int q = 0; q < 13; ++q) acc[q] = 0.f;
  for (int sub = 0; sub < 2; ++sub) {
    int vbase = blockIdx.x * 128 + sub * 64;
    if (vbase >= NV) break;  // uniform per block
    // load shapedirs columns: 30 rows of 192 contiguous floats
    for (int idx = tid; idx < 5760; idx += 256) {
      int k = idx / 192, i = idx - k * 192;
      int g = vbase * 3 + i;
      As[i / 3][k * 3 + (i % 3)] = (g < V3) ? shapedirs[k * V3 + g] : 0.f;
    }
    if (tid < 192) {
      int g = vbase * 3 + tid;
      As[tid / 3][90 + (tid % 3)] = (g < V3) ? v_template[g] : 0.f;
    }
    for (int idx = tid; idx < 2240; idx += 256) {
      int vi = idx / 35, j = idx - vi * 35;
      int v = vbase + vi;
      Jl[vi][j] = (v < NV) ? Jreg[v * 35 + j] : 0.f;
    }
    __syncthreads();
    #pragma unroll
    for (int q = 0; q < 13; ++q) {
      int o = tid + q * 256;
      if (o < 3255) {
        int m = o / 35, j = o - m * 35;
        float a = 0.f;
        #pragma unroll 8
        for (int vi = 0; vi < 64; ++vi) a += As[vi][m] * Jl[vi][j];
        acc[q] += a;
      }
    }
    __syncthreads();
  }
  #pragma unroll
  for (int q = 0; q < 13; ++q) {
    int o = tid + q * 256;
    if (o < 3255) {
      int m = o / 35, j = o - m * 35;
      if (m < 90) {
        int k = m / 3, c = m - k * 3;
        atomicAdd(&SJ[k * 105 + j * 3 + c], acc[q]);
      } else {
        atomicAdd(&J0[j * 3 + (m - 90)], acc[q]);
      }
    }
  }
}

// ---- Rodrigues: Rs to d_out, pose_feature into f[b][30..335]
__global__ __launch_bounds__(256) void k_rodrig(const float* __restrict__ theta,
    float* __restrict__ rs_out, float* __restrict__ f) {
  int idx = blockIdx.x * 256 + threadIdx.x;
  if (idx >= BATCH * NJ) return;
  int b = idx / NJ, j = idx - b * NJ;
  float x = theta[idx * 3 + 0], y = theta[idx * 3 + 1], z = theta[idx * 3 + 2];
  float ax = x + 1e-8f, ay = y + 1e-8f, az = z + 1e-8f;
  float angle = sqrtf(ax * ax + ay * ay + az * az);
  float inv = 1.f / angle;
  float rx = x * inv, ry = y * inv, rz = z * inv;
  float c = cosf(angle), s = sinf(angle), ic = 1.f - c;
  float R[9];
  R[0] = c + ic * rx * rx;      R[1] = ic * rx * ry - s * rz; R[2] = ic * rx * rz + s * ry;
  R[3] = ic * ry * rx + s * rz; R[4] = c + ic * ry * ry;      R[5] = ic * ry * rz - s * rx;
  R[6] = ic * rz * rx - s * ry; R[7] = ic * rz * ry + s * rx; R[8] = c + ic * rz * rz;
  float* ro = rs_out + (size_t)idx * 9;
  #pragma unroll
  for (int e = 0; e < 9; ++e) ro[e] = R[e];
  if (j > 0) {
    float* fp = f + b * NK + 30 + (j - 1) * 9;
    #pragma unroll
    for (int e = 0; e < 9; ++e) fp[e] = R[e] - ((e == 0 || e == 4 || e == 8) ? 1.f : 0.f);
  }
}

// ---- J = J0 + beta@SJ ; scales = exp(mask-gather of betas_limbs) ; f[b][0..29] = beta
__global__ __launch_bounds__(256) void k_jscale(const float* __restrict__ beta,
    const float* __restrict__ bl, const float* __restrict__ SJ, const float* __restrict__ J0,
    float* __restrict__ Jw, float* __restrict__ Sw, float* __restrict__ f) {
  int idx = blockIdx.x * 256 + threadIdx.x;
  if (idx >= BATCH * 105) return;
  int b = idx / 105, jc = idx - b * 105;
  const float* be = beta + b * 30;
  float acc = J0[jc];
  #pragma unroll
  for (int k = 0; k < 30; ++k) acc += be[k] * SJ[k * 105 + jc];
  Jw[idx] = acc;
  int si = d_scale_idx[jc];
  Sw[idx] = (si >= 0) ? expf(bl[b * 7 + si]) : 1.f;
  if (jc < 30) f[b * NK + jc] = be[jc];
}

// ---- kinematic chain: fully unrolled, register-resident (live set = cur + A6/A16/A32)
__device__ __forceinline__ void chain_step(int i, int p, const float* __restrict__ Rsb,
    const float* __restrict__ Jb, const float* __restrict__ Sb,
    const float* Ap, float* Ai) {
  float si0 = Sb[i * 3], si1 = Sb[i * 3 + 1], si2 = Sb[i * 3 + 2];
  float ip0 = 1.f / Sb[p * 3], ip1 = 1.f / Sb[p * 3 + 1], ip2 = 1.f / Sb[p * 3 + 2];
  const float* R = Rsb + i * 9;
  float Ri[9];
  Ri[0] = R[0] * si0 * ip0; Ri[1] = R[1] * si1 * ip0; Ri[2] = R[2] * si2 * ip0;
  Ri[3] = R[3] * si0 * ip1; Ri[4] = R[4] * si1 * ip1; Ri[5] = R[5] * si2 * ip1;
  Ri[6] = R[6] * si0 * ip2; Ri[7] = R[7] * si1 * ip2; Ri[8] = R[8] * si2 * ip2;
  float t0 = Jb[i * 3] - Jb[p * 3], t1 = Jb[i * 3 + 1] - Jb[p * 3 + 1], t2 = Jb[i * 3 + 2] - Jb[p * 3 + 2];
  #pragma unroll
  for (int r = 0; r < 3; ++r) {
    float a = Ap[r * 3], b = Ap[r * 3 + 1], c = Ap[r * 3 + 2];
    float tp = Ap[9 + r];
    Ai[r * 3 + 0] = a * Ri[0] + b * Ri[3] + c * Ri[6];
    Ai[r * 3 + 1] = a * Ri[1] + b * Ri[4] + c * Ri[7];
    Ai[r * 3 + 2] = a * Ri[2] + b * Ri[5] + c * Ri[8];
    Ai[9 + r] = a * t0 + b * t1 + c * t2 + tp;
  }
}

__device__ __forceinline__ void chain_out(int i, const float* __restrict__ Jb,
                                          const float* A, float* __restrict__ O) {
  float jx = Jb[i * 3], jy = Jb[i * 3 + 1], jz = Jb[i * 3 + 2];
  float* o = O + i * 12;
  #pragma unroll
  for (int e = 0; e < 9; ++e) o[e] = A[e];
  o[9]  = A[9]  - (A[0] * jx + A[1] * jy + A[2] * jz);
  o[10] = A[10] - (A[3] * jx + A[4] * jy + A[5] * jz);
  o[11] = A[11] - (A[6] * jx + A[7] * jy + A[8] * jz);
}

__global__ __launch_bounds__(64) void k_chain(const float* __restrict__ rs,
    const float* __restrict__ Jw, const float* __restrict__ Sw, float* __restrict__ Aw) {
  int b = blockIdx.x * 64 + threadIdx.x;
  const float* Rsb = rs + (size_t)b * 315;
  const float* Jb = Jw + b * 105;
  const float* Sb = Sw + b * 105;
  float* O = Aw + (size_t)b * 420;
  float cur[12], A6[12], A16[12], A32[12];
  // root
  #pragma unroll
  for (int e = 0; e < 9; ++e) cur[e] = Rsb[e];
  cur[9] = Jb[0]; cur[10] = Jb[1]; cur[11] = Jb[2];
  chain_out(0, Jb, cur, O);
#define STEP(i, p, SRC) { chain_step(i, p, Rsb, Jb, Sb, SRC, cur); chain_out(i, Jb, cur, O); }
  STEP(1, 0, cur) STEP(2, 1, cur) STEP(3, 2, cur) STEP(4, 3, cur) STEP(5, 4, cur) STEP(6, 5, cur)
  #pragma unroll
  for (int e = 0; e < 12; ++e) A6[e] = cur[e];
  STEP(7, 6, A6) STEP(8, 7, cur) STEP(9, 8, cur) STEP(10, 9, cur) STEP(11, 10, cur)
  STEP(12, 6, A6) STEP(13, 12, cur) STEP(14, 13, cur) STEP(15, 14, cur)
  STEP(16, 6, A6)
  #pragma unroll
  for (int e = 0; e < 12; ++e) A16[e] = cur[e];
  STEP(17, 16, A16) STEP(18, 17, cur) STEP(19, 18, cur)
  STEP(20, 16, A16) STEP(21, 20, cur) STEP(22, 21, cur) STEP(23, 22, cur)
  STEP(24, 16, A16) STEP(25, 24, cur) STEP(26, 25, cur) STEP(27, 26, cur)
  STEP(28, 27, cur) STEP(29, 28, cur) STEP(30, 29, cur) STEP(31, 30, cur)
  STEP(32, 16, A16)
  #pragma unroll
  for (int e = 0; e < 12; ++e) A32[e] = cur[e];
  STEP(33, 32, A32)
  STEP(34, 32, A32)
#undef STEP
}

// ---- big GEMM: v_posed[b, col] = v_template[col] + sum_k f[b,k]*D[k,col]
// 128x128 tile, Kc=48, 8x8 per-thread register blocking; B-cols split tx*4 / tx*4+64
__global__ __launch_bounds__(256) void k_gemm(const float* __restrict__ f,
    const float* __restrict__ shapedirs, const float* __restrict__ posedirs,
    const float* __restrict__ v_template, float* __restrict__ v_posed) {
  __shared__ float fT[48][140];  // [k][row]
  __shared__ float Dl[48][136];  // [k][col]
  int tid = threadIdx.x;
  int n0 = blockIdx.x * 128;
  int b0 = blockIdx.y * 128;
  int tx = tid & 15, ty = tid >> 4;
  float acc[8][8];
  #pragma unroll
  for (int r = 0; r < 8; ++r)
    #pragma unroll
    for (int c = 0; c < 8; ++c) acc[r][c] = 0.f;
  for (int kt = 0; kt < 7; ++kt) {
    int k0 = kt * 48;
    for (int i = tid; i < 6144; i += 256) {
      int k = i % 48, row = i / 48;
      fT[k][row] = f[(b0 + row) * NK + k0 + k];
    }
    for (int i = tid; i < 6144; i += 256) {
      int col = i & 127, k = i >> 7;
      int gc = n0 + col, gk = k0 + k;
      float v = 0.f;
      if (gc < V3) v = (gk < 30) ? shapedirs[gk * V3 + gc] : posedirs[(size_t)(gk - 30) * V3 + gc];
      Dl[k][col] = v;
    }
    __syncthreads();
    #pragma unroll 4
    for (int k = 0; k < 48; ++k) {
      float4 a0 = *(const float4*)&fT[k][ty * 8];
      float4 a1 = *(const float4*)&fT[k][ty * 8 + 4];
      float4 q0 = *(const float4*)&Dl[k][tx * 4];
      float4 q1 = *(const float4*)&Dl[k][tx * 4 + 64];
      float av[8] = {a0.x, a0.y, a0.z, a0.w, a1.x, a1.y, a1.z, a1.w};
      float bv[8] = {q0.x, q0.y, q0.z, q0.w, q1.x, q1.y, q1.z, q1.w};
      #pragma unroll
      for (int r = 0; r < 8; ++r)
        #pragma unroll
        for (int c = 0; c < 8; ++c) acc[r][c] += av[r] * bv[c];
    }
    __syncthreads();
  }
  int col0 = n0 + tx * 4;
  int col1 = col0 + 64;
  float tv[8];
  #pragma unroll
  for (int c = 0; c < 4; ++c) tv[c] = (col0 + c < V3) ? v_template[col0 + c] : 0.f;
  #pragma unroll
  for (int c = 0; c < 4; ++c) tv[4 + c] = (col1 + c < V3) ? v_template[col1 + c] : 0.f;
  #pragma unroll
  for (int r = 0; r < 8; ++r) {
    int row = b0 + ty * 8 + r;
    float* dst = v_posed + (size_t)row * VPS;
    if (col0 + 4 <= V3) {
      *(float4*)(dst + col0) = make_float4(acc[r][0] + tv[0], acc[r][1] + tv[1],
                                           acc[r][2] + tv[2], acc[r][3] + tv[3]);
    } else {
      #pragma unroll
      for (int c = 0; c < 4; ++c)
        if (col0 + c < V3) dst[col0 + c] = acc[r][c] + tv[c];
    }
    if (col1 + 4 <= V3) {
      *(float4*)(dst + col1) = make_float4(acc[r][4] + tv[4], acc[r][5] + tv[5],
                                           acc[r][6] + tv[6], acc[r][7] + tv[7]);
    } else {
      #pragma unroll
      for (int c = 0; c < 4; ++c)
        if (col1 + c < V3) dst[col1 + c] = acc[r][4 + c] + tv[4 + c];
    }
  }
}

// ---- skinning: verts = (sum_j w*A_R)@p + sum_j w*A_t + trans
__global__ __launch_bounds__(256) void k_skin(const float* __restrict__ Aw,
    const float* __restrict__ weights, const float* __restrict__ v_posed,
    const float* __restrict__ trans, float* __restrict__ verts) {
  __shared__ float wl[256][37];
  __shared__ float Al[4][420];
  int tid = threadIdx.x;
  int v0 = blockIdx.x * 256;
  int b0 = blockIdx.y * 4;
  for (int i = tid; i < 256 * 35; i += 256) {
    int vl = i / 35, j = i - vl * 35;
    int v = v0 + vl;
    wl[vl][j] = (v < NV) ? weights[v * 35 + j] : 0.f;
  }
  for (int i = tid; i < 4 * 420; i += 256) {
    int b = i / 420, e = i - b * 420;
    Al[b][e] = Aw[(b0 + b) * 420 + e];
  }
  __syncthreads();
  int bb = tid >> 6, l = tid & 63;
  int gb = b0 + bb;
  float M[4][12];
  #pragma unroll
  for (int q = 0; q < 4; ++q)
    #pragma unroll
    for (int e = 0; e < 12; ++e) M[q][e] = 0.f;
  for (int j = 0; j < 35; ++j) {
    float4 A0 = *(const float4*)&Al[bb][j * 12];
    float4 A1 = *(const float4*)&Al[bb][j * 12 + 4];
    float4 A2 = *(const float4*)&Al[bb][j * 12 + 8];
    #pragma unroll
    for (int q = 0; q < 4; ++q) {
      float wj = wl[l + 64 * q][j];
      M[q][0] += wj * A0.x; M[q][1] += wj * A0.y; M[q][2] += wj * A0.z; M[q][3] += wj * A0.w;
      M[q][4] += wj * A1.x; M[q][5] += wj * A1.y; M[q][6] += wj * A1.z; M[q][7] += wj * A1.w;
      M[q][8] += wj * A2.x; M[q][9] += wj * A2.y; M[q][10] += wj * A2.z; M[q][11] += wj * A2.w;
    }
  }
  float t0 = trans[gb * 3], t1 = trans[gb * 3 + 1], t2 = trans[gb * 3 + 2];
  #pragma unroll
  for (int q = 0; q < 4; ++q) {
    int v = v0 + l + 64 * q;
    if (v < NV) {
      const float* p = &v_posed[(size_t)gb * VPS + v * 3];
      float p0 = p[0], p1 = p[1], p2 = p[2];
      float* o = verts + (size_t)gb * V3 + v * 3;
      o[0] = M[q][0] * p0 + M[q][1] * p1 + M[q][2] * p2 + M[q][9] + t0;
      o[1] = M[q][3] * p0 + M[q][4] * p1 + M[q][5] * p2 + M[q][10] + t1;
      o[2] = M[q][6] * p0 + M[q][7] * p1 + M[q][8] * p2 + M[q][11] + t2;
    }
  }
}

// ---- joints_red = verts . J_regressor  (atomic partial sums over v-slices)
__global__ __launch_bounds__(256) void k_joints(const float* __restrict__ verts,
    const float* __restrict__ Jreg, float* __restrict__ joints) {
  __shared__ float vt_lds[16][388];
  __shared__ float jr_lds[128][36];
  int tid = threadIdx.x;
  int b0 = blockIdx.x * 16;
  int vstart = blockIdx.y * 487;
  int vend = min(NV, vstart + 487);
  int bl = tid & 15, jg = tid >> 4;
  int j0 = jg, j1 = jg + 16, j2 = jg + 32;
  bool has2 = (j2 < 35);
  float acc[3][3];
  #pragma unroll
  for (int s = 0; s < 3; ++s)
    #pragma unroll
    for (int c = 0; c < 3; ++c) acc[s][c] = 0.f;
  for (int vt = vstart; vt < vend; vt += 128) {
    int nv = min(128, vend - vt);
    for (int i = tid; i < 16 * 384; i += 256) {
      int bb = i / 384, e = i - bb * 384;
      float val = 0.f;
      if (e < nv * 3) val = verts[(size_t)(b0 + bb) * V3 + vt * 3 + e];
      vt_lds[bb][e] = val;
    }
    for (int i = tid; i < 128 * 35; i += 256) {
      int vl = i / 35, j = i - vl * 35;
      int v = vt + vl;
      jr_lds[vl][j] = (v < vend) ? Jreg[v * 35 + j] : 0.f;
    }
    __syncthreads();
    for (int v = 0; v < nv; ++v) {
      float p0 = vt_lds[bl][v * 3 + 0];
      float p1 = vt_lds[bl][v * 3 + 1];
      float p2 = vt_lds[bl][v * 3 + 2];
      float jr0 = jr_lds[v][j0];
      acc[0][0] += jr0 * p0; acc[0][1] += jr0 * p1; acc[0][2] += jr0 * p2;
      float jr1 = jr_lds[v][j1];
      acc[1][0] += jr1 * p0; acc[1][1] += jr1 * p1; acc[1][2] += jr1 * p2;
      if (has2) {
        float jr2 = jr_lds[v][j2];
        acc[2][0] += jr2 * p0; acc[2][1] += jr2 * p1; acc[2][2] += jr2 * p2;
      }
    }
    __syncthreads();
  }
  int gb = b0 + bl;
  atomicAdd(&joints[gb * 105 + j0 * 3 + 0], acc[0][0]);
  atomicAdd(&joints[gb * 105 + j0 * 3 + 1], acc[0][1]);
  atomicAdd(&joints[gb * 105 + j0 * 3 + 2], acc[0][2]);
  atomicAdd(&joints[gb * 105 + j1 * 3 + 0], acc[1][0]);
  atomicAdd(&joints[gb * 105 + j1 * 3 + 1], acc[1][1]);
  atomicAdd(&joints[gb * 105 + j1 * 3 + 2], acc[1][2]);
  if (has2) {
    atomicAdd(&joints[gb * 105 + j2 * 3 + 0], acc[2][0]);
    atomicAdd(&joints[gb * 105 + j2 * 3 + 1], acc[2][1]);
    atomicAdd(&joints[gb * 105 + j2 * 3 + 2], acc[2][2]);
  }
}

extern "C" void kernel_launch(void* const* d_in, const int* in_sizes, int n_in,
                              void* d_out, int out_size, void* d_ws, size_t ws_size,
                              hipStream_t stream) {
  const float* beta = (const float*)d_in[0];
  const float* betas_limbs = (const float*)d_in[1];
  const float* theta = (const float*)d_in[2];
  const float* trans = (const float*)d_in[3];
  const float* v_template = (const float*)d_in[4];
  const float* shapedirs = (const float*)d_in[5];
  const float* Jreg = (const float*)d_in[6];
  const float* posedirs = (const float*)d_in[7];
  const float* weights = (const float*)d_in[8];

  float* out = (float*)d_out;
  float* verts = out;
  float* joints = out + OUT_JOINTS;
  float* rsout = out + OUT_RS;

  float* ws = (float*)d_ws;
  float* SJ = ws + WS_SJ;
  float* J0 = ws + WS_J0;
  float* f = ws + WS_F;
  float* Jw = ws + WS_JW;
  float* Sw = ws + WS_SW;
  float* Aw = ws + WS_AW;
  float* vposed = ws + WS_VP;

  hipMemsetAsync(ws, 0, 3264 * sizeof(float), stream);             // SJ + J0
  hipMemsetAsync(joints, 0, BATCH * 105 * sizeof(float), stream);  // joints accumulators

  k_precomp<<<31, 256, 0, stream>>>(shapedirs, v_template, Jreg, SJ, J0);
  k_rodrig<<<140, 256, 0, stream>>>(theta, rsout, f);
  k_jscale<<<420, 256, 0, stream>>>(beta, betas_limbs, SJ, J0, Jw, Sw, f);
  k_chain<<<16, 64, 0, stream>>>(rsout, Jw, Sw, Aw);
  k_gemm<<<dim3(92, 8), 256, 0, stream>>>(f, shapedirs, posedirs, v_template, vposed);
  k_skin<<<dim3(16, 256), 256, 0, stream>>>(Aw, weights, vposed, trans, verts);
  k_joints<<<dim3(64, 8), 256, 0, stream>>>(verts, Jreg, joints);
}

// Round 12
// 455.833 us; speedup vs baseline: 1.4536x; 1.0777x over previous
//
#include <hip/hip_runtime.h>

#define BATCH 1024
#define NV 3889
#define V3 11667
#define NJ 35
#define NK 336
#define NKP 352     // K padded to 11*32 for MFMA
#define DTR 11776   // Dt rows (92*128), cols >= V3 zero-filled
#define VPS 11680   // padded v_posed row stride

// ws layout (floats) — identical to round-1 (known-safe 51.8MB)
#define WS_SJ 0          // 30*105
#define WS_J0 3152       // 105
#define WS_F 3264        // 1024*336
#define WS_JW 347328     // 1024*105
#define WS_SW 454848     // 1024*105
#define WS_AW 562368     // 1024*420
#define WS_VP 992448     // 1024*VPS

// d_out offsets (floats)
#define OUT_JOINTS 11947008
#define OUT_RS 12054528
// bf16 scratch inside the verts region of d_out (overwritten later by k_skin)
#define DT_HI_F 0         // DTR*NKP ushorts = 2072576 floats
#define DT_LO_F 2072576
#define FBF_HI_F 4145152  // 1024*NKP ushorts = 180224 floats
#define FBF_LO_F 4325376  // end 4505600 << 11947008

typedef __attribute__((ext_vector_type(8))) short bf16x8;
typedef __attribute__((ext_vector_type(4))) float f32x4;

__device__ __forceinline__ unsigned short f2bf(float x) {
  unsigned u = __float_as_uint(x);
  unsigned r = u + 0x7FFFu + ((u >> 16) & 1u);
  return (unsigned short)(r >> 16);
}
__device__ __forceinline__ float bf2f(unsigned short h) {
  return __uint_as_float(((unsigned)h) << 16);
}

__device__ const signed char d_scale_idx[105] = {
  -1,-1,-1, -1,-1,-1, -1,-1,-1, -1,-1,-1, -1,-1,-1, -1,-1,-1, -1,-1,-1, // j0..6
   1, 1, 0,  1, 1, 0,  1, 1, 0,  1, 1, 0,                               // j7..10
  -1,-1,-1, -1,-1,-1, -1,-1,-1, -1,-1,-1, -1,-1,-1,                     // j11..15
   6,-1,-1,                                                             // j16
   1, 1, 0,  1, 1, 0,  1, 1, 0,  1, 1, 0,                               // j17..20
  -1,-1,-1, -1,-1,-1, -1,-1,-1, -1,-1,-1,                               // j21..24
   2, 3, 3,  2, 3, 3,  2, 3, 3,  2, 3, 3,  2, 3, 3,  2, 3, 3,  2, 3, 3, // j25..31
  -1,-1,-1,                                                             // j32
  -1, 4, 5, -1, 4, 5                                                    // j33..34
};

// ---- SJ[k][j*3+c] = sum_v shapedirs[k, v*3+c]*Jreg[v,j];  J0 likewise from v_template
__global__ __launch_bounds__(256) void k_precomp(const float* __restrict__ shapedirs,
    const float* __restrict__ v_template, const float* __restrict__ Jreg,
    float* __restrict__ SJ, float* __restrict__ J0) {
  __shared__ float As[64][96];
  __shared__ float Jl[64][36];
  int tid = threadIdx.x;
  float acc[13];
  #pragma unroll
  for (int q = 0; q < 13; ++q) acc[q] = 0.f;
  for (int sub = 0; sub < 2; ++sub) {
    int vbase = blockIdx.x * 128 + sub * 64;
    if (vbase >= NV) break;
    for (int idx = tid; idx < 5760; idx += 256) {
      int k = idx / 192, i = idx - k * 192;
      int g = vbase * 3 + i;
      As[i / 3][k * 3 + (i % 3)] = (g < V3) ? shapedirs[k * V3 + g] : 0.f;
    }
    if (tid < 192) {
      int g = vbase * 3 + tid;
      As[tid / 3][90 + (tid % 3)] = (g < V3) ? v_template[g] : 0.f;
    }
    for (int idx = tid; idx < 2240; idx += 256) {
      int vi = idx / 35, j = idx - vi * 35;
      int v = vbase + vi;
      Jl[vi][j] = (v < NV) ? Jreg[v * 35 + j] : 0.f;
    }
    __syncthreads();
    #pragma unroll
    for (int q = 0; q < 13; ++q) {
      int o = tid + q * 256;
      if (o < 3255) {
        int m = o / 35, j = o - m * 35;
        float a = 0.f;
        #pragma unroll 8
        for (int vi = 0; vi < 64; ++vi) a += As[vi][m] * Jl[vi][j];
        acc[q] += a;
      }
    }
    __syncthreads();
  }
  #pragma unroll
  for (int q = 0; q < 13; ++q) {
    int o = tid + q * 256;
    if (o < 3255) {
      int m = o / 35, j = o - m * 35;
      if (m < 90) {
        int k = m / 3, c = m - k * 3;
        atomicAdd(&SJ[k * 105 + j * 3 + c], acc[q]);
      } else {
        atomicAdd(&J0[j * 3 + (m - 90)], acc[q]);
      }
    }
  }
}

// ---- transpose + bf16 hi/lo split of D=[shapedirs;posedirs] -> Dt[n][k], zero-padded
__global__ __launch_bounds__(256) void k_prep_dt(const float* __restrict__ shapedirs,
    const float* __restrict__ posedirs, unsigned short* __restrict__ dt_hi,
    unsigned short* __restrict__ dt_lo) {
  __shared__ float Tl[64 * 177];
  int tid = threadIdx.x;
  int n0 = blockIdx.x * 64;
  for (int c = 0; c < 2; ++c) {
    int k0 = c * 176;
    for (int i = tid; i < 176 * 64; i += 256) {
      int r = i >> 6, cc = i & 63;
      int gk = k0 + r, gn = n0 + cc;
      float v = 0.f;
      if (gk < NK && gn < V3)
        v = (gk < 30) ? shapedirs[gk * V3 + gn] : posedirs[(size_t)(gk - 30) * V3 + gn];
      Tl[cc * 177 + r] = v;
    }
    __syncthreads();
    for (int i = tid; i < 64 * 176; i += 256) {
      int cc = i / 176, r = i - cc * 176;
      float x = Tl[cc * 177 + r];
      unsigned short h = f2bf(x);
      size_t o = (size_t)(n0 + cc) * NKP + k0 + r;
      dt_hi[o] = h;
      dt_lo[o] = f2bf(x - bf2f(h));
    }
    __syncthreads();
  }
}

// ---- Rodrigues: Rs to d_out, pose_feature into f[b][30..335]
__global__ __launch_bounds__(256) void k_rodrig(const float* __restrict__ theta,
    float* __restrict__ rs_out, float* __restrict__ f) {
  int idx = blockIdx.x * 256 + threadIdx.x;
  if (idx >= BATCH * NJ) return;
  int b = idx / NJ, j = idx - b * NJ;
  float x = theta[idx * 3 + 0], y = theta[idx * 3 + 1], z = theta[idx * 3 + 2];
  float ax = x + 1e-8f, ay = y + 1e-8f, az = z + 1e-8f;
  float angle = sqrtf(ax * ax + ay * ay + az * az);
  float inv = 1.f / angle;
  float rx = x * inv, ry = y * inv, rz = z * inv;
  float c = cosf(angle), s = sinf(angle), ic = 1.f - c;
  float R[9];
  R[0] = c + ic * rx * rx;      R[1] = ic * rx * ry - s * rz; R[2] = ic * rx * rz + s * ry;
  R[3] = ic * ry * rx + s * rz; R[4] = c + ic * ry * ry;      R[5] = ic * ry * rz - s * rx;
  R[6] = ic * rz * rx - s * ry; R[7] = ic * rz * ry + s * rx; R[8] = c + ic * rz * rz;
  float* ro = rs_out + (size_t)idx * 9;
  #pragma unroll
  for (int e = 0; e < 9; ++e) ro[e] = R[e];
  if (j > 0) {
    float* fp = f + b * NK + 30 + (j - 1) * 9;
    #pragma unroll
    for (int e = 0; e < 9; ++e) fp[e] = R[e] - ((e == 0 || e == 4 || e == 8) ? 1.f : 0.f);
  }
}

// ---- J = J0 + beta@SJ ; scales ; f[b][0..29] = beta
__global__ __launch_bounds__(256) void k_jscale(const float* __restrict__ beta,
    const float* __restrict__ bl, const float* __restrict__ SJ, const float* __restrict__ J0,
    float* __restrict__ Jw, float* __restrict__ Sw, float* __restrict__ f) {
  int idx = blockIdx.x * 256 + threadIdx.x;
  if (idx >= BATCH * 105) return;
  int b = idx / 105, jc = idx - b * 105;
  const float* be = beta + b * 30;
  float acc = J0[jc];
  #pragma unroll
  for (int k = 0; k < 30; ++k) acc += be[k] * SJ[k * 105 + jc];
  Jw[idx] = acc;
  int si = d_scale_idx[jc];
  Sw[idx] = (si >= 0) ? expf(bl[b * 7 + si]) : 1.f;
  if (jc < 30) f[b * NK + jc] = be[jc];
}

// ---- f (fp32, stride 336) -> bf16 hi/lo padded to 352
__global__ __launch_bounds__(256) void k_convf(const float* __restrict__ f,
    unsigned short* __restrict__ fh, unsigned short* __restrict__ fl) {
  int idx = blockIdx.x * 256 + threadIdx.x;
  if (idx >= BATCH * NKP) return;
  int b = idx / NKP, k = idx - b * NKP;
  float x = (k < NK) ? f[b * NK + k] : 0.f;
  unsigned short h = f2bf(x);
  fh[idx] = h;
  fl[idx] = f2bf(x - bf2f(h));
}

// ---- kinematic chain: fully unrolled, register-resident
__device__ __forceinline__ void chain_step(int i, int p, const float* __restrict__ Rsb,
    const float* __restrict__ Jb, const float* __restrict__ Sb,
    const float* Ap, float* Ai) {
  float si0 = Sb[i * 3], si1 = Sb[i * 3 + 1], si2 = Sb[i * 3 + 2];
  float ip0 = 1.f / Sb[p * 3], ip1 = 1.f / Sb[p * 3 + 1], ip2 = 1.f / Sb[p * 3 + 2];
  const float* R = Rsb + i * 9;
  float Ri[9];
  Ri[0] = R[0] * si0 * ip0; Ri[1] = R[1] * si1 * ip0; Ri[2] = R[2] * si2 * ip0;
  Ri[3] = R[3] * si0 * ip1; Ri[4] = R[4] * si1 * ip1; Ri[5] = R[5] * si2 * ip1;
  Ri[6] = R[6] * si0 * ip2; Ri[7] = R[7] * si1 * ip2; Ri[8] = R[8] * si2 * ip2;
  float t0 = Jb[i * 3] - Jb[p * 3], t1 = Jb[i * 3 + 1] - Jb[p * 3 + 1], t2 = Jb[i * 3 + 2] - Jb[p * 3 + 2];
  #pragma unroll
  for (int r = 0; r < 3; ++r) {
    float a = Ap[r * 3], b = Ap[r * 3 + 1], c = Ap[r * 3 + 2];
    float tp = Ap[9 + r];
    Ai[r * 3 + 0] = a * Ri[0] + b * Ri[3] + c * Ri[6];
    Ai[r * 3 + 1] = a * Ri[1] + b * Ri[4] + c * Ri[7];
    Ai[r * 3 + 2] = a * Ri[2] + b * Ri[5] + c * Ri[8];
    Ai[9 + r] = a * t0 + b * t1 + c * t2 + tp;
  }
}

__device__ __forceinline__ void chain_out(int i, const float* __restrict__ Jb,
                                          const float* A, float* __restrict__ O) {
  float jx = Jb[i * 3], jy = Jb[i * 3 + 1], jz = Jb[i * 3 + 2];
  float* o = O + i * 12;
  #pragma unroll
  for (int e = 0; e < 9; ++e) o[e] = A[e];
  o[9]  = A[9]  - (A[0] * jx + A[1] * jy + A[2] * jz);
  o[10] = A[10] - (A[3] * jx + A[4] * jy + A[5] * jz);
  o[11] = A[11] - (A[6] * jx + A[7] * jy + A[8] * jz);
}

__global__ __launch_bounds__(64) void k_chain(const float* __restrict__ rs,
    const float* __restrict__ Jw, const float* __restrict__ Sw, float* __restrict__ Aw) {
  int b = blockIdx.x * 64 + threadIdx.x;
  const float* Rsb = rs + (size_t)b * 315;
  const float* Jb = Jw + b * 105;
  const float* Sb = Sw + b * 105;
  float* O = Aw + (size_t)b * 420;
  float cur[12], A6[12], A16[12], A32[12];
  #pragma unroll
  for (int e = 0; e < 9; ++e) cur[e] = Rsb[e];
  cur[9] = Jb[0]; cur[10] = Jb[1]; cur[11] = Jb[2];
  chain_out(0, Jb, cur, O);
#define STEP(i, p, SRC) { chain_step(i, p, Rsb, Jb, Sb, SRC, cur); chain_out(i, Jb, cur, O); }
  STEP(1, 0, cur) STEP(2, 1, cur) STEP(3, 2, cur) STEP(4, 3, cur) STEP(5, 4, cur) STEP(6, 5, cur)
  #pragma unroll
  for (int e = 0; e < 12; ++e) A6[e] = cur[e];
  STEP(7, 6, A6) STEP(8, 7, cur) STEP(9, 8, cur) STEP(10, 9, cur) STEP(11, 10, cur)
  STEP(12, 6, A6) STEP(13, 12, cur) STEP(14, 13, cur) STEP(15, 14, cur)
  STEP(16, 6, A6)
  #pragma unroll
  for (int e = 0; e < 12; ++e) A16[e] = cur[e];
  STEP(17, 16, A16) STEP(18, 17, cur) STEP(19, 18, cur)
  STEP(20, 16, A16) STEP(21, 20, cur) STEP(22, 21, cur) STEP(23, 22, cur)
  STEP(24, 16, A16) STEP(25, 24, cur) STEP(26, 25, cur) STEP(27, 26, cur)
  STEP(28, 27, cur) STEP(29, 28, cur) STEP(30, 29, cur) STEP(31, 30, cur)
  STEP(32, 16, A16)
  #pragma unroll
  for (int e = 0; e < 12; ++e) A32[e] = cur[e];
  STEP(33, 32, A32)
  STEP(34, 32, A32)
#undef STEP
}

// ---- MFMA GEMM: v_posed[b,col] = v_template[col] + sum_k f[b,k]*D[k,col]
// hi/lo bf16 split (3 MFMA products), wave = 64x64 output, no LDS (L2-direct frags).
// A frag: row = lane&15, k = (lane>>4)*8 + j ; B frag: col = lane&15, same k.
// C frag: col = lane&15, row = (lane>>4)*4 + reg  [m89-verified]
__global__ __launch_bounds__(256) void k_gemm_mfma(
    const unsigned short* __restrict__ dt_hi, const unsigned short* __restrict__ dt_lo,
    const unsigned short* __restrict__ fh, const unsigned short* __restrict__ fl,
    const float* __restrict__ v_template, float* __restrict__ v_posed) {
  int tid = threadIdx.x;
  int wave = tid >> 6, lane = tid & 63;
  int wm = wave >> 1, wn = wave & 1;
  int b0 = blockIdx.y * 128 + wm * 64;
  int n0 = blockIdx.x * 128 + wn * 64;
  int lr = lane & 15, lg = lane >> 4;

  f32x4 acc[4][4];
  #pragma unroll
  for (int mi = 0; mi < 4; ++mi)
    #pragma unroll
    for (int ni = 0; ni < 4; ++ni) acc[mi][ni] = (f32x4)(0.f);

  const unsigned short* Ah = fh + (size_t)(b0 + lr) * NKP + lg * 8;
  const unsigned short* Al = fl + (size_t)(b0 + lr) * NKP + lg * 8;
  const unsigned short* Bh = dt_hi + (size_t)(n0 + lr) * NKP + lg * 8;
  const unsigned short* Bl = dt_lo + (size_t)(n0 + lr) * NKP + lg * 8;

  for (int kk = 0; kk < 11; ++kk) {
    int ko = kk * 32;
    bf16x8 ah[4], al[4], bh[4], bl4[4];
    #pragma unroll
    for (int i = 0; i < 4; ++i) {
      ah[i]  = *(const bf16x8*)(Ah + (size_t)i * 16 * NKP + ko);
      al[i]  = *(const bf16x8*)(Al + (size_t)i * 16 * NKP + ko);
      bh[i]  = *(const bf16x8*)(Bh + (size_t)i * 16 * NKP + ko);
      bl4[i] = *(const bf16x8*)(Bl + (size_t)i * 16 * NKP + ko);
    }
    #pragma unroll
    for (int mi = 0; mi < 4; ++mi)
      #pragma unroll
      for (int ni = 0; ni < 4; ++ni) {
        acc[mi][ni] = __builtin_amdgcn_mfma_f32_16x16x32_bf16(ah[mi], bh[ni],  acc[mi][ni], 0, 0, 0);
        acc[mi][ni] = __builtin_amdgcn_mfma_f32_16x16x32_bf16(ah[mi], bl4[ni], acc[mi][ni], 0, 0, 0);
        acc[mi][ni] = __builtin_amdgcn_mfma_f32_16x16x32_bf16(al[mi], bh[ni],  acc[mi][ni], 0, 0, 0);
      }
  }

  #pragma unroll
  for (int ni = 0; ni < 4; ++ni) {
    int col = n0 + ni * 16 + lr;
    if (col < V3) {
      float tv = v_template[col];
      #pragma unroll
      for (int mi = 0; mi < 4; ++mi) {
        int rowb = b0 + mi * 16 + lg * 4;
        #pragma unroll
        for (int r = 0; r < 4; ++r)
          v_posed[(size_t)(rowb + r) * VPS + col] = acc[mi][ni][r] + tv;
      }
    }
  }
}

// ---- skinning: verts = (sum_j w*A_R)@p + sum_j w*A_t + trans
__global__ __launch_bounds__(256) void k_skin(const float* __restrict__ Aw,
    const float* __restrict__ weights, const float* __restrict__ v_posed,
    const float* __restrict__ trans, float* __restrict__ verts) {
  __shared__ float wl[256][37];
  __shared__ float Al[4][420];
  int tid = threadIdx.x;
  int v0 = blockIdx.x * 256;
  int b0 = blockIdx.y * 4;
  for (int i = tid; i < 256 * 35; i += 256) {
    int vl = i / 35, j = i - vl * 35;
    int v = v0 + vl;
    wl[vl][j] = (v < NV) ? weights[v * 35 + j] : 0.f;
  }
  for (int i = tid; i < 4 * 420; i += 256) {
    int b = i / 420, e = i - b * 420;
    Al[b][e] = Aw[(b0 + b) * 420 + e];
  }
  __syncthreads();
  int bb = tid >> 6, l = tid & 63;
  int gb = b0 + bb;
  float M[4][12];
  #pragma unroll
  for (int q = 0; q < 4; ++q)
    #pragma unroll
    for (int e = 0; e < 12; ++e) M[q][e] = 0.f;
  for (int j = 0; j < 35; ++j) {
    float4 A0 = *(const float4*)&Al[bb][j * 12];
    float4 A1 = *(const float4*)&Al[bb][j * 12 + 4];
    float4 A2 = *(const float4*)&Al[bb][j * 12 + 8];
    #pragma unroll
    for (int q = 0; q < 4; ++q) {
      float wj = wl[l + 64 * q][j];
      M[q][0] += wj * A0.x; M[q][1] += wj * A0.y; M[q][2] += wj * A0.z; M[q][3] += wj * A0.w;
      M[q][4] += wj * A1.x; M[q][5] += wj * A1.y; M[q][6] += wj * A1.z; M[q][7] += wj * A1.w;
      M[q][8] += wj * A2.x; M[q][9] += wj * A2.y; M[q][10] += wj * A2.z; M[q][11] += wj * A2.w;
    }
  }
  float t0 = trans[gb * 3], t1 = trans[gb * 3 + 1], t2 = trans[gb * 3 + 2];
  #pragma unroll
  for (int q = 0; q < 4; ++q) {
    int v = v0 + l + 64 * q;
    if (v < NV) {
      const float* p = &v_posed[(size_t)gb * VPS + v * 3];
      float p0 = p[0], p1 = p[1], p2 = p[2];
      float* o = verts + (size_t)gb * V3 + v * 3;
      o[0] = M[q][0] * p0 + M[q][1] * p1 + M[q][2] * p2 + M[q][9] + t0;
      o[1] = M[q][3] * p0 + M[q][4] * p1 + M[q][5] * p2 + M[q][10] + t1;
      o[2] = M[q][6] * p0 + M[q][7] * p1 + M[q][8] * p2 + M[q][11] + t2;
    }
  }
}

// ---- joints_red = verts . J_regressor
__global__ __launch_bounds__(256) void k_joints(const float* __restrict__ verts,
    const float* __restrict__ Jreg, float* __restrict__ joints) {
  __shared__ float vt_lds[16][388];
  __shared__ float jr_lds[128][36];
  int tid = threadIdx.x;
  int b0 = blockIdx.x * 16;
  int vstart = blockIdx.y * 487;
  int vend = min(NV, vstart + 487);
  int bl = tid & 15, jg = tid >> 4;
  int j0 = jg, j1 = jg + 16, j2 = jg + 32;
  bool has2 = (j2 < 35);
  float acc[3][3];
  #pragma unroll
  for (int s = 0; s < 3; ++s)
    #pragma unroll
    for (int c = 0; c < 3; ++c) acc[s][c] = 0.f;
  for (int vt = vstart; vt < vend; vt += 128) {
    int nv = min(128, vend - vt);
    for (int i = tid; i < 16 * 384; i += 256) {
      int bb = i / 384, e = i - bb * 384;
      float val = 0.f;
      if (e < nv * 3) val = verts[(size_t)(b0 + bb) * V3 + vt * 3 + e];
      vt_lds[bb][e] = val;
    }
    for (int i = tid; i < 128 * 35; i += 256) {
      int vl = i / 35, j = i - vl * 35;
      int v = vt + vl;
      jr_lds[vl][j] = (v < vend) ? Jreg[v * 35 + j] : 0.f;
    }
    __syncthreads();
    for (int v = 0; v < nv; ++v) {
      float p0 = vt_lds[bl][v * 3 + 0];
      float p1 = vt_lds[bl][v * 3 + 1];
      float p2 = vt_lds[bl][v * 3 + 2];
      float jr0 = jr_lds[v][j0];
      acc[0][0] += jr0 * p0; acc[0][1] += jr0 * p1; acc[0][2] += jr0 * p2;
      float jr1 = jr_lds[v][j1];
      acc[1][0] += jr1 * p0; acc[1][1] += jr1 * p1; acc[1][2] += jr1 * p2;
      if (has2) {
        float jr2 = jr_lds[v][j2];
        acc[2][0] += jr2 * p0; acc[2][1] += jr2 * p1; acc[2][2] += jr2 * p2;
      }
    }
    __syncthreads();
  }
  int gb = b0 + bl;
  atomicAdd(&joints[gb * 105 + j0 * 3 + 0], acc[0][0]);
  atomicAdd(&joints[gb * 105 + j0 * 3 + 1], acc[0][1]);
  atomicAdd(&joints[gb * 105 + j0 * 3 + 2], acc[0][2]);
  atomicAdd(&joints[gb * 105 + j1 * 3 + 0], acc[1][0]);
  atomicAdd(&joints[gb * 105 + j1 * 3 + 1], acc[1][1]);
  atomicAdd(&joints[gb * 105 + j1 * 3 + 2], acc[1][2]);
  if (has2) {
    atomicAdd(&joints[gb * 105 + j2 * 3 + 0], acc[2][0]);
    atomicAdd(&joints[gb * 105 + j2 * 3 + 1], acc[2][1]);
    atomicAdd(&joints[gb * 105 + j2 * 3 + 2], acc[2][2]);
  }
}

extern "C" void kernel_launch(void* const* d_in, const int* in_sizes, int n_in,
                              void* d_out, int out_size, void* d_ws, size_t ws_size,
                              hipStream_t stream) {
  const float* beta = (const float*)d_in[0];
  const float* betas_limbs = (const float*)d_in[1];
  const float* theta = (const float*)d_in[2];
  const float* trans = (const float*)d_in[3];
  const float* v_template = (const float*)d_in[4];
  const float* shapedirs = (const float*)d_in[5];
  const float* Jreg = (const float*)d_in[6];
  const float* posedirs = (const float*)d_in[7];
  const float* weights = (const float*)d_in[8];

  float* out = (float*)d_out;
  float* verts = out;
  float* joints = out + OUT_JOINTS;
  float* rsout = out + OUT_RS;

  unsigned short* dt_hi = (unsigned short*)(out + DT_HI_F);
  unsigned short* dt_lo = (unsigned short*)(out + DT_LO_F);
  unsigned short* fbf_hi = (unsigned short*)(out + FBF_HI_F);
  unsigned short* fbf_lo = (unsigned short*)(out + FBF_LO_F);

  float* ws = (float*)d_ws;
  float* SJ = ws + WS_SJ;
  float* J0 = ws + WS_J0;
  float* f = ws + WS_F;
  float* Jw = ws + WS_JW;
  float* Sw = ws + WS_SW;
  float* Aw = ws + WS_AW;
  float* vposed = ws + WS_VP;

  hipMemsetAsync(ws, 0, 3264 * sizeof(float), stream);             // SJ + J0
  hipMemsetAsync(joints, 0, BATCH * 105 * sizeof(float), stream);  // joints accumulators

  k_prep_dt<<<184, 256, 0, stream>>>(shapedirs, posedirs, dt_hi, dt_lo);
  k_precomp<<<31, 256, 0, stream>>>(shapedirs, v_template, Jreg, SJ, J0);
  k_rodrig<<<140, 256, 0, stream>>>(theta, rsout, f);
  k_jscale<<<420, 256, 0, stream>>>(beta, betas_limbs, SJ, J0, Jw, Sw, f);
  k_convf<<<1408, 256, 0, stream>>>(f, fbf_hi, fbf_lo);
  k_chain<<<16, 64, 0, stream>>>(rsout, Jw, Sw, Aw);
  k_gemm_mfma<<<dim3(92, 8), 256, 0, stream>>>(dt_hi, dt_lo, fbf_hi, fbf_lo, v_template, vposed);
  k_skin<<<dim3(16, 256), 256, 0, stream>>>(Aw, weights, vposed, trans, verts);
  k_joints<<<dim3(64, 8), 256, 0, stream>>>(verts, Jreg, joints);
}